// Round 11
// baseline (320.431 us; speedup 1.0000x reference)
//
#include <hip/hip_runtime.h>
#include <hip/hip_bf16.h>
#include <math.h>

// B=4, N1=2048, N2=1024, IN=768, OUT=1024, H=16, DH=64
// d_out = att_probs fp32 [4,16,1024,2048] ++ out fp32 [4,1024,1024]

typedef __attribute__((ext_vector_type(8))) short short8;
typedef __attribute__((ext_vector_type(4))) float f32x4;

__device__ __forceinline__ ushort f2b(float f) {
  __hip_bfloat16 h = __float2bfloat16(f);
  return *reinterpret_cast<ushort*>(&h);
}

__device__ __forceinline__ void gload16(const ushort* g, ushort* lds) {
  __builtin_amdgcn_global_load_lds(
      (const __attribute__((address_space(1))) unsigned int*)g,
      (__attribute__((address_space(3))) unsigned int*)lds, 16, 0, 0);
}

__device__ __forceinline__ float wave_red_sum(float v) {
#pragma unroll
  for (int o = 32; o; o >>= 1) v += __shfl_down(v, o);
  return v;
}

// ---------------- prep: fused weight-cvt + both LayerNorms -----------------
__device__ __forceinline__ void ln_row(const float* __restrict__ x,
                                       const float* __restrict__ g,
                                       const float* __restrict__ bta,
                                       ushort* __restrict__ y, int D) {
  int nv = D >> 2;
  float s = 0.f, s2 = 0.f;
  for (int i = threadIdx.x; i < nv; i += 256) {
    float4 v = ((const float4*)x)[i];
    s += v.x + v.y + v.z + v.w;
    s2 += v.x * v.x + v.y * v.y + v.z * v.z + v.w * v.w;
  }
  s = wave_red_sum(s);
  s2 = wave_red_sum(s2);
  __shared__ float red[8];
  int wid = threadIdx.x >> 6, lane = threadIdx.x & 63;
  if (lane == 0) { red[wid] = s; red[4 + wid] = s2; }
  __syncthreads();
  float ts = red[0] + red[1] + red[2] + red[3];
  float t2 = red[4] + red[5] + red[6] + red[7];
  float mu = ts / (float)D;
  float rstd = rsqrtf(t2 / (float)D - mu * mu + 1e-5f);
  for (int i = threadIdx.x; i < nv; i += 256) {
    float4 v = ((const float4*)x)[i];
    float4 gg = ((const float4*)g)[i];
    float4 bb = ((const float4*)bta)[i];
    ushort4 o;
    o.x = f2b((v.x - mu) * rstd * gg.x + bb.x);
    o.y = f2b((v.y - mu) * rstd * gg.y + bb.y);
    o.z = f2b((v.z - mu) * rstd * gg.z + bb.z);
    o.w = f2b((v.w - mu) * rstd * gg.w + bb.w);
    ((ushort4*)y)[i] = o;
  }
}

// blocks [0,3584): weight cvt (917504 float4s). [3584,15872): LN rows.
__global__ __launch_bounds__(256) void prep_kernel(
    const float* __restrict__ s0, ushort* __restrict__ d0,
    const float* __restrict__ s1, ushort* __restrict__ d1,
    const float* __restrict__ s2, ushort* __restrict__ d2,
    const float* __restrict__ s3, ushort* __restrict__ d3,
    const float* __restrict__ inA, const float* __restrict__ gA,
    const float* __restrict__ bA, ushort* __restrict__ yA,
    const float* __restrict__ inB, const float* __restrict__ gB,
    const float* __restrict__ bB, ushort* __restrict__ yB) {
  int blk = blockIdx.x;
  if (blk < 3584) {
    int i = blk * 256 + threadIdx.x;
    const float* s;
    ushort* d;
    int j = i;
    if (i < 262144) { s = s0; d = d0; }
    else if (i < 458752) { s = s1; d = d1; j = i - 262144; }
    else if (i < 655360) { s = s2; d = d2; j = i - 458752; }
    else { s = s3; d = d3; j = i - 655360; }
    float4 v = ((const float4*)s)[j];
    ushort4 o;
    o.x = f2b(v.x); o.y = f2b(v.y); o.z = f2b(v.z); o.w = f2b(v.w);
    ((ushort4*)d)[j] = o;
  } else {
    size_t r = blk - 3584;
    if (r < 8192)
      ln_row(inA + r * 768, gA, bA, yA + r * 768, 768);
    else {
      size_t rr = r - 8192;
      ln_row(inB + rr * 1024, gB, bB, yB + rr * 1024, 1024);
    }
  }
}

// ---------------- fused QKV GEMMs: one launch, 1280 blocks, 128x128 tile ---
// m97 structure: [128][32] dbuf LDS via gload_lds w16, vmcnt(4), 16 MFMA/step.
// blocks [0,256): q = o_ln@q_w^T+q_b      M=4096 N=1024 K=1024
// blocks [256,768): k = i_ln@k_w^T+k_b    M=8192 N=1024 K=768
// blocks [768,1280): vt[z] = v_w@i_ln[z]^T + v_b[row]  M=1024 N=2048 K=768
__global__ __launch_bounds__(256) void qkv_kernel(
    const ushort* __restrict__ o_ln, const ushort* __restrict__ i_ln,
    const ushort* __restrict__ qwb, const ushort* __restrict__ kwb,
    const ushort* __restrict__ vwb, const float* __restrict__ q_b,
    const float* __restrict__ k_b, const float* __restrict__ v_b,
    ushort* __restrict__ qb, ushort* __restrict__ kb,
    ushort* __restrict__ vt) {
  __shared__ __align__(16) ushort As[2][128 * 32];
  __shared__ __align__(16) ushort Ws[2][128 * 32];

  int id = blockIdx.x;
  const ushort *A, *W;
  const float* bias;
  ushort* C;
  int K, lda, ldc, bx, by, biasmode;
  long long coff = 0;
  if (id < 256) {
    A = o_ln; W = qwb; bias = q_b; C = qb;
    K = 1024; lda = 1024; ldc = 1024;
    bx = id & 31; by = id >> 5; biasmode = 1;
  } else if (id < 768) {
    int t = id - 256;
    A = i_ln; W = kwb; bias = k_b; C = kb;
    K = 768; lda = 768; ldc = 1024;
    bx = t & 63; by = t >> 6; biasmode = 1;
  } else {
    int t = id - 768;
    int z = t >> 7, r = t & 127;
    A = vwb; W = i_ln + (size_t)z * 1572864; bias = v_b; C = vt;
    coff = (long long)z * 2097152;
    K = 768; lda = 768; ldc = 2048;
    bx = r & 7; by = r >> 3; biasmode = 2;
  }

  const ushort* Ab = A + (size_t)bx * 128 * lda;
  const ushort* Wb = W + (size_t)by * 128 * lda;  // ldw == lda for all three
  int tid = threadIdx.x, l = tid & 63, w = tid >> 6;
  int wr = w >> 1, wc = w & 1;
  f32x4 acc[4][4];
#pragma unroll
  for (int i = 0; i < 4; ++i)
#pragma unroll
    for (int j = 0; j < 4; ++j) acc[i][j] = (f32x4){0.f, 0.f, 0.f, 0.f};

  int srow = l >> 2, scol = (l & 3) * 8;
  int lr = l & 15, lk = (l >> 4) * 8;

#define STAGE(bb, k0)                                                       \
  do {                                                                      \
    const ushort* ga = Ab + (size_t)(w * 16 + srow) * lda + (k0) + scol;    \
    const ushort* gw = Wb + (size_t)(w * 16 + srow) * lda + (k0) + scol;    \
    gload16(ga, &As[bb][(w * 16) * 32]);                                    \
    gload16(ga + (size_t)64 * lda, &As[bb][(w * 16 + 64) * 32]);            \
    gload16(gw, &Ws[bb][(w * 16) * 32]);                                    \
    gload16(gw + (size_t)64 * lda, &Ws[bb][(w * 16 + 64) * 32]);            \
  } while (0)

  int nk = K >> 5;
  STAGE(0, 0);
  for (int t = 0; t < nk; ++t) {
    int cur = t & 1;
    if (t + 1 < nk) {
      STAGE(cur ^ 1, (t + 1) * 32);
      asm volatile("s_waitcnt vmcnt(4)" ::: "memory");
    } else {
      asm volatile("s_waitcnt vmcnt(0)" ::: "memory");
    }
    __builtin_amdgcn_s_barrier();
    __builtin_amdgcn_sched_barrier(0);
    short8 af[4], bf[4];
#pragma unroll
    for (int fi = 0; fi < 4; ++fi)
      af[fi] = *(const short8*)&As[cur][(wr * 64 + fi * 16 + lr) * 32 + lk];
#pragma unroll
    for (int fj = 0; fj < 4; ++fj)
      bf[fj] = *(const short8*)&Ws[cur][(wc * 64 + fj * 16 + lr) * 32 + lk];
    __builtin_amdgcn_s_setprio(1);
#pragma unroll
    for (int fi = 0; fi < 4; ++fi)
#pragma unroll
      for (int fj = 0; fj < 4; ++fj)
        acc[fi][fj] = __builtin_amdgcn_mfma_f32_16x16x32_bf16(
            af[fi], bf[fj], acc[fi][fj], 0, 0, 0);
    __builtin_amdgcn_s_setprio(0);
    __builtin_amdgcn_s_barrier();
  }
#undef STAGE

  int m0 = bx * 128, n0 = by * 128;
#pragma unroll
  for (int fi = 0; fi < 4; ++fi)
#pragma unroll
    for (int fj = 0; fj < 4; ++fj) {
      int col = n0 + wc * 64 + fj * 16 + lr;
      float bv = (biasmode == 1) ? bias[col] : 0.f;
#pragma unroll
      for (int r4 = 0; r4 < 4; ++r4) {
        int row = m0 + wr * 64 + fi * 16 + (l >> 4) * 4 + r4;
        float val = acc[fi][fj][r4] + bv;
        if (biasmode == 2) val += bias[row];
        C[coff + (size_t)row * ldc + col] = f2b(val);
      }
    }
}

// ---------------- proj GEMM: 128x64, fp32 out + residual, triple-buffered --
__global__ __launch_bounds__(256) void proj_kernel(
    const ushort* __restrict__ A, const ushort* __restrict__ W,
    const float* __restrict__ bias, const float* __restrict__ resid,
    float* __restrict__ C) {
  __shared__ __align__(16) ushort As[3][128 * 32];
  __shared__ __align__(16) ushort Ws[3][64 * 32];
  const int lda = 1024, ldw = 1024, ldc = 1024, nk = 32;
  const ushort* Ab = A + (size_t)blockIdx.x * 128 * lda;
  const ushort* Wb = W + (size_t)blockIdx.y * 64 * ldw;
  int tid = threadIdx.x, l = tid & 63, w = tid >> 6;
  int wr = w >> 1, wc = w & 1;
  f32x4 acc[4][2];
#pragma unroll
  for (int i = 0; i < 4; ++i)
#pragma unroll
    for (int j = 0; j < 2; ++j) acc[i][j] = (f32x4){0.f, 0.f, 0.f, 0.f};

  int srow = l >> 2, scol = (l & 3) * 8;
  int lr = l & 15, lk = (l >> 4) * 8;

#define STAGE(bb, k0)                                                       \
  do {                                                                      \
    const ushort* ga = Ab + (size_t)(w * 32 + srow) * lda + (k0) + scol;    \
    gload16(ga, &As[bb][(w * 32) * 32]);                                    \
    gload16(ga + (size_t)16 * lda, &As[bb][(w * 32 + 16) * 32]);            \
    gload16(Wb + (size_t)(w * 16 + srow) * ldw + (k0) + scol,               \
            &Ws[bb][(w * 16) * 32]);                                        \
  } while (0)

  STAGE(0, 0);
  STAGE(1, 32);
  int cur = 0;
  for (int t = 0; t < nk; ++t) {
    if (t + 2 < nk) {
      int slot = cur + 2;
      if (slot >= 3) slot -= 3;
      STAGE(slot, (t + 2) * 32);
      asm volatile("s_waitcnt vmcnt(6)" ::: "memory");
    } else if (t + 1 < nk) {
      asm volatile("s_waitcnt vmcnt(3)" ::: "memory");
    } else {
      asm volatile("s_waitcnt vmcnt(0)" ::: "memory");
    }
    __builtin_amdgcn_s_barrier();
    __builtin_amdgcn_sched_barrier(0);
    short8 af[4], bf[2];
#pragma unroll
    for (int fi = 0; fi < 4; ++fi)
      af[fi] = *(const short8*)&As[cur][(wr * 64 + fi * 16 + lr) * 32 + lk];
#pragma unroll
    for (int fj = 0; fj < 2; ++fj)
      bf[fj] = *(const short8*)&Ws[cur][(wc * 32 + fj * 16 + lr) * 32 + lk];
    __builtin_amdgcn_s_setprio(1);
#pragma unroll
    for (int fi = 0; fi < 4; ++fi)
#pragma unroll
      for (int fj = 0; fj < 2; ++fj)
        acc[fi][fj] = __builtin_amdgcn_mfma_f32_16x16x32_bf16(
            af[fi], bf[fj], acc[fi][fj], 0, 0, 0);
    __builtin_amdgcn_s_setprio(0);
    __builtin_amdgcn_s_barrier();
    cur = cur + 1;
    if (cur >= 3) cur -= 3;
  }
#undef STAGE

  int m0 = blockIdx.x * 128, n0 = blockIdx.y * 64;
#pragma unroll
  for (int fi = 0; fi < 4; ++fi)
#pragma unroll
    for (int fj = 0; fj < 2; ++fj) {
      int col = n0 + wc * 32 + fj * 16 + lr;
      float bv = bias[col];
#pragma unroll
      for (int r4 = 0; r4 < 4; ++r4) {
        int row = m0 + wr * 64 + fi * 16 + (l >> 4) * 4 + r4;
        C[(size_t)row * ldc + col] =
            acc[fi][fj][r4] + bv + resid[(size_t)row * ldc + col];
      }
    }
}

// ---------------- Fused flash attention: 128 Q-rows/block, max-free SM -----
// grid 512 blocks XCD-swizzled -> (bh, mtile of 128 rows). 4 waves; each wave
// owns rows [w*16,w*16+16) and [64+w*16,64+w*16+16) (2 fragments).
// Per K/V tile: one dbuf staging + one lgkm-only barrier serves both frags.
__global__ __launch_bounds__(256, 2) void attn_kernel(
    const ushort* __restrict__ qb, const ushort* __restrict__ kb,
    const ushort* __restrict__ vt, float* __restrict__ att,
    ushort* __restrict__ ctrl) {
  __shared__ ushort QP_lds[128 * 72];   // Q tile then P tile (wave-local rows)
  __shared__ ushort K_lds[2][64 * 72];
  __shared__ ushort V_lds[2][64 * 72];

  int bid = blockIdx.x;
  int vv = ((bid & 7) << 6) + (bid >> 3);  // 8 XCDs x 64: 8 bh per XCD
  int bh = vv >> 3, mt = vv & 7;
  int b = bh >> 4, h = bh & 15;
  int m0 = mt * 128;
  int tid = threadIdx.x, l = tid & 63, w = tid >> 6;
  int lr = l & 15, lk = (l >> 4) * 8;
  int klo = (l >> 4) * 4;

  const float SC = 0.125f * 1.44269504088896f;  // 1/8 * log2(e)

  // stage Q tile [128 rows][64 d]
#pragma unroll
  for (int it = 0; it < 4; ++it) {
    int idx = tid + it * 256;
    int row = idx >> 3, c8 = (idx & 7) * 8;
    *(uint4*)&QP_lds[row * 72 + c8] = *(const uint4*)(
        qb + (size_t)(b * 1024 + m0 + row) * 1024 + h * 64 + c8);
  }
  __syncthreads();
  short8 aq[2][2];
#pragma unroll
  for (int f = 0; f < 2; ++f) {
    aq[f][0] = *(const short8*)&QP_lds[(f * 64 + w * 16 + lr) * 72 + lk];
    aq[f][1] = *(const short8*)&QP_lds[(f * 64 + w * 16 + lr) * 72 + 32 + lk];
  }
  __syncthreads();  // QP_lds free for P use after this

  const size_t kbase = (size_t)b * 2048 * 1024 + h * 64;
  const ushort* Kb = kb + kbase;
  int srow = tid >> 3, sc8 = (tid & 7) * 8;

  float ls[2] = {0.f, 0.f};

  // ---- pass A: row sums (max-free; scores bounded) ----
  uint4 kr0 = *(const uint4*)(Kb + (size_t)srow * 1024 + sc8);
  uint4 kr1 = *(const uint4*)(Kb + (size_t)(srow + 32) * 1024 + sc8);
  for (int t = 0; t < 32; ++t) {
    int cur = t & 1;
    *(uint4*)&K_lds[cur][srow * 72 + sc8] = kr0;
    *(uint4*)&K_lds[cur][(srow + 32) * 72 + sc8] = kr1;
    asm volatile("s_waitcnt lgkmcnt(0)" ::: "memory");
    __builtin_amdgcn_s_barrier();
    __builtin_amdgcn_sched_barrier(0);
    if (t < 31) {
      kr0 = *(const uint4*)(Kb + (size_t)(t * 64 + 64 + srow) * 1024 + sc8);
      kr1 = *(const uint4*)(Kb + (size_t)(t * 64 + 96 + srow) * 1024 + sc8);
    }
#pragma unroll
    for (int f = 0; f < 2; ++f) {
      f32x4 acc[4];
      __builtin_amdgcn_s_setprio(1);
#pragma unroll
      for (int fj = 0; fj < 4; ++fj) {
        short8 kf0 = *(const short8*)&K_lds[cur][(fj * 16 + lr) * 72 + lk];
        short8 kf1 =
            *(const short8*)&K_lds[cur][(fj * 16 + lr) * 72 + 32 + lk];
        f32x4 a = (f32x4){0.f, 0.f, 0.f, 0.f};
        a = __builtin_amdgcn_mfma_f32_16x16x32_bf16(kf0, aq[f][0], a, 0, 0, 0);
        a = __builtin_amdgcn_mfma_f32_16x16x32_bf16(kf1, aq[f][1], a, 0, 0, 0);
        acc[fj] = a;
      }
      __builtin_amdgcn_s_setprio(0);
#pragma unroll
      for (int fj = 0; fj < 4; ++fj)
#pragma unroll
        for (int r = 0; r < 4; ++r) ls[f] += exp2f(acc[fj][r] * SC);
    }
  }
  float mb[2];
#pragma unroll
  for (int f = 0; f < 2; ++f) {
    float s = ls[f];
    s += __shfl_xor(s, 16);
    s += __shfl_xor(s, 32);
    mb[f] = __log2f(s);  // p = exp2(score*SC - mb)
  }

  // ---- pass B: emit P + PV ----
  float* attp = att + (size_t)bh * 2048 * 1024 + (size_t)m0 * 2048;
  const ushort* Vb = vt + (size_t)bh * 64 * 2048;
  f32x4 acco[2][4];
#pragma unroll
  for (int f = 0; f < 2; ++f)
#pragma unroll
    for (int fd = 0; fd < 4; ++fd) acco[f][fd] = (f32x4){0.f, 0.f, 0.f, 0.f};

  kr0 = *(const uint4*)(Kb + (size_t)srow * 1024 + sc8);
  kr1 = *(const uint4*)(Kb + (size_t)(srow + 32) * 1024 + sc8);
  uint4 vr0 = *(const uint4*)(Vb + (size_t)srow * 2048 + sc8);
  uint4 vr1 = *(const uint4*)(Vb + (size_t)(srow + 32) * 2048 + sc8);
  for (int t = 0; t < 32; ++t) {
    int cur = t & 1;
    int k0 = t * 64;
    *(uint4*)&K_lds[cur][srow * 72 + sc8] = kr0;
    *(uint4*)&K_lds[cur][(srow + 32) * 72 + sc8] = kr1;
    *(uint4*)&V_lds[cur][srow * 72 + sc8] = vr0;
    *(uint4*)&V_lds[cur][(srow + 32) * 72 + sc8] = vr1;
    asm volatile("s_waitcnt lgkmcnt(0)" ::: "memory");
    __builtin_amdgcn_s_barrier();
    __builtin_amdgcn_sched_barrier(0);
    if (t < 31) {
      kr0 = *(const uint4*)(Kb + (size_t)(k0 + 64 + srow) * 1024 + sc8);
      kr1 = *(const uint4*)(Kb + (size_t)(k0 + 96 + srow) * 1024 + sc8);
      vr0 = *(const uint4*)(Vb + (size_t)srow * 2048 + k0 + 64 + sc8);
      vr1 = *(const uint4*)(Vb + (size_t)(srow + 32) * 2048 + k0 + 64 + sc8);
    }
    // QK^T both fragments
    f32x4 acc[2][4];
    __builtin_amdgcn_s_setprio(1);
#pragma unroll
    for (int fj = 0; fj < 4; ++fj) {
      short8 kf0 = *(const short8*)&K_lds[cur][(fj * 16 + lr) * 72 + lk];
      short8 kf1 = *(const short8*)&K_lds[cur][(fj * 16 + lr) * 72 + 32 + lk];
#pragma unroll
      for (int f = 0; f < 2; ++f) {
        f32x4 a = (f32x4){0.f, 0.f, 0.f, 0.f};
        a = __builtin_amdgcn_mfma_f32_16x16x32_bf16(kf0, aq[f][0], a, 0, 0, 0);
        a = __builtin_amdgcn_mfma_f32_16x16x32_bf16(kf1, aq[f][1], a, 0, 0, 0);
        acc[f][fj] = a;
      }
    }
    __builtin_amdgcn_s_setprio(0);
    // emit normalized P for both fragments
#pragma unroll
    for (int f = 0; f < 2; ++f) {
      int qrow = f * 64 + w * 16 + lr;
#pragma unroll
      for (int fj = 0; fj < 4; ++fj) {
        f32x4 p;
        p[0] = exp2f(fmaf(acc[f][fj][0], SC, -mb[f]));
        p[1] = exp2f(fmaf(acc[f][fj][1], SC, -mb[f]));
        p[2] = exp2f(fmaf(acc[f][fj][2], SC, -mb[f]));
        p[3] = exp2f(fmaf(acc[f][fj][3], SC, -mb[f]));
        __builtin_nontemporal_store(
            p, (f32x4*)(attp + (size_t)qrow * 2048 + k0 + fj * 16 + klo));
        union { uint2 u; ushort s[4]; } pk;
        pk.s[0] = f2b(p[0]);
        pk.s[1] = f2b(p[1]);
        pk.s[2] = f2b(p[2]);
        pk.s[3] = f2b(p[3]);
        *(uint2*)&QP_lds[qrow * 72 + fj * 16 + klo] = pk.u;
      }
    }
    // PV: shared V reads serve both fragments
    short8 ap[2][2];
#pragma unroll
    for (int f = 0; f < 2; ++f) {
      ap[f][0] = *(const short8*)&QP_lds[(f * 64 + w * 16 + lr) * 72 + lk];
      ap[f][1] =
          *(const short8*)&QP_lds[(f * 64 + w * 16 + lr) * 72 + 32 + lk];
    }
    __builtin_amdgcn_s_setprio(1);
#pragma unroll
    for (int fd = 0; fd < 4; ++fd) {
      short8 bv0 = *(const short8*)&V_lds[cur][(fd * 16 + lr) * 72 + lk];
      short8 bv1 = *(const short8*)&V_lds[cur][(fd * 16 + lr) * 72 + 32 + lk];
#pragma unroll
      for (int f = 0; f < 2; ++f) {
        acco[f][fd] = __builtin_amdgcn_mfma_f32_16x16x32_bf16(
            ap[f][0], bv0, acco[f][fd], 0, 0, 0);
        acco[f][fd] = __builtin_amdgcn_mfma_f32_16x16x32_bf16(
            ap[f][1], bv1, acco[f][fd], 0, 0, 0);
      }
    }
    __builtin_amdgcn_s_setprio(0);
  }

#pragma unroll
  for (int f = 0; f < 2; ++f)
#pragma unroll
    for (int fd = 0; fd < 4; ++fd)
#pragma unroll
      for (int r = 0; r < 4; ++r) {
        int wrow = f * 64 + w * 16 + (l >> 4) * 4 + r;
        ctrl[(size_t)(b * 1024 + m0 + wrow) * 1024 + h * 64 + fd * 16 + lr] =
            f2b(acco[f][fd][r]);
      }
}

extern "C" void kernel_launch(void* const* d_in, const int* in_sizes, int n_in,
                              void* d_out, int out_size, void* d_ws,
                              size_t ws_size, hipStream_t stream) {
  const float* input = (const float*)d_in[0];
  const float* output = (const float*)d_in[1];
  const float* q_w = (const float*)d_in[2];
  const float* q_b = (const float*)d_in[3];
  const float* k_w = (const float*)d_in[4];
  const float* k_b = (const float*)d_in[5];
  const float* v_w = (const float*)d_in[6];
  const float* v_b = (const float*)d_in[7];
  const float* p_w = (const float*)d_in[8];
  const float* p_b = (const float*)d_in[9];
  const float* ln_in_g = (const float*)d_in[10];
  const float* ln_in_b = (const float*)d_in[11];
  const float* ln_out_g = (const float*)d_in[12];
  const float* ln_out_b = (const float*)d_in[13];

  ushort* ws = (ushort*)d_ws;
  ushort* i_ln = ws;                    // 4*2048*768  = 6291456
  ushort* o_ln = i_ln + 6291456;        // 4194304
  ushort* qb = o_ln + 4194304;          // 4194304
  ushort* kb = qb + 4194304;            // 8388608
  ushort* vt = kb + 8388608;            // 8388608  [4][1024 d][2048 k]
  ushort* ctrl = vt + 8388608;          // 4194304
  ushort* qwb = ctrl + 4194304;         // 1048576
  ushort* kwb = qwb + 1048576;          // 786432
  ushort* vwb = kwb + 786432;           // 786432
  ushort* pwb = vwb + 786432;           // 1048576

  float* att = (float*)d_out;
  float* out2 = att + 134217728LL;

  // prep: weight cvt + both LNs, one launch
  prep_kernel<<<15872, 256, 0, stream>>>(q_w, qwb, k_w, kwb, v_w, vwb, p_w,
                                         pwb, input, ln_in_g, ln_in_b, i_ln,
                                         output, ln_out_g, ln_out_b, o_ln);

  // q + k + vt GEMMs in one launch (128x128 tiles)
  qkv_kernel<<<1280, 256, 0, stream>>>(o_ln, i_ln, qwb, kwb, vwb, q_b, k_b,
                                       v_b, qb, kb, vt);

  // fused attention: scores + softmax + P-write + PV (128 Q-rows/block)
  attn_kernel<<<dim3(512), 256, 0, stream>>>(qb, kb, vt, att, ctrl);

  // out = output + ctrl @ proj_w^T + proj_b (fp32) M=4096 N=1024 K=1024
  proj_kernel<<<dim3(32, 16), 256, 0, stream>>>(ctrl, pwb, p_b, output, out2);
}

// Round 12
// 273.336 us; speedup vs baseline: 1.1723x; 1.1723x over previous
//
#include <hip/hip_runtime.h>
#include <hip/hip_bf16.h>
#include <math.h>

// B=4, N1=2048, N2=1024, IN=768, OUT=1024, H=16, DH=64
// d_out = att_probs fp32 [4,16,1024,2048] ++ out fp32 [4,1024,1024]

typedef __attribute__((ext_vector_type(8))) short short8;
typedef __attribute__((ext_vector_type(4))) float f32x4;

__device__ __forceinline__ ushort f2b(float f) {
  __hip_bfloat16 h = __float2bfloat16(f);
  return *reinterpret_cast<ushort*>(&h);
}

__device__ __forceinline__ void gload16(const ushort* g, ushort* lds) {
  __builtin_amdgcn_global_load_lds(
      (const __attribute__((address_space(1))) unsigned int*)g,
      (__attribute__((address_space(3))) unsigned int*)lds, 16, 0, 0);
}

__device__ __forceinline__ float wave_red_sum(float v) {
#pragma unroll
  for (int o = 32; o; o >>= 1) v += __shfl_down(v, o);
  return v;
}

// ---------------- prep: fused weight-cvt + both LayerNorms -----------------
__device__ __forceinline__ void ln_row(const float* __restrict__ x,
                                       const float* __restrict__ g,
                                       const float* __restrict__ bta,
                                       ushort* __restrict__ y, int D) {
  int nv = D >> 2;
  float s = 0.f, s2 = 0.f;
  for (int i = threadIdx.x; i < nv; i += 256) {
    float4 v = ((const float4*)x)[i];
    s += v.x + v.y + v.z + v.w;
    s2 += v.x * v.x + v.y * v.y + v.z * v.z + v.w * v.w;
  }
  s = wave_red_sum(s);
  s2 = wave_red_sum(s2);
  __shared__ float red[8];
  int wid = threadIdx.x >> 6, lane = threadIdx.x & 63;
  if (lane == 0) { red[wid] = s; red[4 + wid] = s2; }
  __syncthreads();
  float ts = red[0] + red[1] + red[2] + red[3];
  float t2 = red[4] + red[5] + red[6] + red[7];
  float mu = ts / (float)D;
  float rstd = rsqrtf(t2 / (float)D - mu * mu + 1e-5f);
  for (int i = threadIdx.x; i < nv; i += 256) {
    float4 v = ((const float4*)x)[i];
    float4 gg = ((const float4*)g)[i];
    float4 bb = ((const float4*)bta)[i];
    ushort4 o;
    o.x = f2b((v.x - mu) * rstd * gg.x + bb.x);
    o.y = f2b((v.y - mu) * rstd * gg.y + bb.y);
    o.z = f2b((v.z - mu) * rstd * gg.z + bb.z);
    o.w = f2b((v.w - mu) * rstd * gg.w + bb.w);
    ((ushort4*)y)[i] = o;
  }
}

// blocks [0,3584): weight cvt (917504 float4s). [3584,15872): LN rows.
__global__ __launch_bounds__(256) void prep_kernel(
    const float* __restrict__ s0, ushort* __restrict__ d0,
    const float* __restrict__ s1, ushort* __restrict__ d1,
    const float* __restrict__ s2, ushort* __restrict__ d2,
    const float* __restrict__ s3, ushort* __restrict__ d3,
    const float* __restrict__ inA, const float* __restrict__ gA,
    const float* __restrict__ bA, ushort* __restrict__ yA,
    const float* __restrict__ inB, const float* __restrict__ gB,
    const float* __restrict__ bB, ushort* __restrict__ yB) {
  int blk = blockIdx.x;
  if (blk < 3584) {
    int i = blk * 256 + threadIdx.x;
    const float* s;
    ushort* d;
    int j = i;
    if (i < 262144) { s = s0; d = d0; }
    else if (i < 458752) { s = s1; d = d1; j = i - 262144; }
    else if (i < 655360) { s = s2; d = d2; j = i - 458752; }
    else { s = s3; d = d3; j = i - 655360; }
    float4 v = ((const float4*)s)[j];
    ushort4 o;
    o.x = f2b(v.x); o.y = f2b(v.y); o.z = f2b(v.z); o.w = f2b(v.w);
    ((ushort4*)d)[j] = o;
  } else {
    size_t r = blk - 3584;
    if (r < 8192)
      ln_row(inA + r * 768, gA, bA, yA + r * 768, 768);
    else {
      size_t rr = r - 8192;
      ln_row(inB + rr * 1024, gB, bB, yB + rr * 1024, 1024);
    }
  }
}

// ---------------- fused QKV GEMMs: one launch, 1280 blocks, 128x128 tile ---
// m97 structure: [128][32] dbuf LDS via gload_lds w16, vmcnt(4), 16 MFMA/step.
// blocks [0,256): q = o_ln@q_w^T+q_b      M=4096 N=1024 K=1024
// blocks [256,768): k = i_ln@k_w^T+k_b    M=8192 N=1024 K=768
// blocks [768,1280): vt[z] = v_w@i_ln[z]^T + v_b[row]  M=1024 N=2048 K=768
__global__ __launch_bounds__(256) void qkv_kernel(
    const ushort* __restrict__ o_ln, const ushort* __restrict__ i_ln,
    const ushort* __restrict__ qwb, const ushort* __restrict__ kwb,
    const ushort* __restrict__ vwb, const float* __restrict__ q_b,
    const float* __restrict__ k_b, const float* __restrict__ v_b,
    ushort* __restrict__ qb, ushort* __restrict__ kb,
    ushort* __restrict__ vt) {
  __shared__ __align__(16) ushort As[2][128 * 32];
  __shared__ __align__(16) ushort Ws[2][128 * 32];

  int id = blockIdx.x;
  const ushort *A, *W;
  const float* bias;
  ushort* C;
  int K, lda, ldc, bx, by, biasmode;
  long long coff = 0;
  if (id < 256) {
    A = o_ln; W = qwb; bias = q_b; C = qb;
    K = 1024; lda = 1024; ldc = 1024;
    bx = id & 31; by = id >> 5; biasmode = 1;
  } else if (id < 768) {
    int t = id - 256;
    A = i_ln; W = kwb; bias = k_b; C = kb;
    K = 768; lda = 768; ldc = 1024;
    bx = t & 63; by = t >> 6; biasmode = 1;
  } else {
    int t = id - 768;
    int z = t >> 7, r = t & 127;
    A = vwb; W = i_ln + (size_t)z * 1572864; bias = v_b; C = vt;
    coff = (long long)z * 2097152;
    K = 768; lda = 768; ldc = 2048;
    bx = r & 7; by = r >> 3; biasmode = 2;
  }

  const ushort* Ab = A + (size_t)bx * 128 * lda;
  const ushort* Wb = W + (size_t)by * 128 * lda;  // ldw == lda for all three
  int tid = threadIdx.x, l = tid & 63, w = tid >> 6;
  int wr = w >> 1, wc = w & 1;
  f32x4 acc[4][4];
#pragma unroll
  for (int i = 0; i < 4; ++i)
#pragma unroll
    for (int j = 0; j < 4; ++j) acc[i][j] = (f32x4){0.f, 0.f, 0.f, 0.f};

  int srow = l >> 2, scol = (l & 3) * 8;
  int lr = l & 15, lk = (l >> 4) * 8;

#define STAGE(bb, k0)                                                       \
  do {                                                                      \
    const ushort* ga = Ab + (size_t)(w * 16 + srow) * lda + (k0) + scol;    \
    const ushort* gw = Wb + (size_t)(w * 16 + srow) * lda + (k0) + scol;    \
    gload16(ga, &As[bb][(w * 16) * 32]);                                    \
    gload16(ga + (size_t)64 * lda, &As[bb][(w * 16 + 64) * 32]);            \
    gload16(gw, &Ws[bb][(w * 16) * 32]);                                    \
    gload16(gw + (size_t)64 * lda, &Ws[bb][(w * 16 + 64) * 32]);            \
  } while (0)

  int nk = K >> 5;
  STAGE(0, 0);
  for (int t = 0; t < nk; ++t) {
    int cur = t & 1;
    if (t + 1 < nk) {
      STAGE(cur ^ 1, (t + 1) * 32);
      asm volatile("s_waitcnt vmcnt(4)" ::: "memory");
    } else {
      asm volatile("s_waitcnt vmcnt(0)" ::: "memory");
    }
    __builtin_amdgcn_s_barrier();
    __builtin_amdgcn_sched_barrier(0);
    short8 af[4], bf[4];
#pragma unroll
    for (int fi = 0; fi < 4; ++fi)
      af[fi] = *(const short8*)&As[cur][(wr * 64 + fi * 16 + lr) * 32 + lk];
#pragma unroll
    for (int fj = 0; fj < 4; ++fj)
      bf[fj] = *(const short8*)&Ws[cur][(wc * 64 + fj * 16 + lr) * 32 + lk];
    __builtin_amdgcn_s_setprio(1);
#pragma unroll
    for (int fi = 0; fi < 4; ++fi)
#pragma unroll
      for (int fj = 0; fj < 4; ++fj)
        acc[fi][fj] = __builtin_amdgcn_mfma_f32_16x16x32_bf16(
            af[fi], bf[fj], acc[fi][fj], 0, 0, 0);
    __builtin_amdgcn_s_setprio(0);
    __builtin_amdgcn_s_barrier();
  }
#undef STAGE

  int m0 = bx * 128, n0 = by * 128;
#pragma unroll
  for (int fi = 0; fi < 4; ++fi)
#pragma unroll
    for (int fj = 0; fj < 4; ++fj) {
      int col = n0 + wc * 64 + fj * 16 + lr;
      float bv = (biasmode == 1) ? bias[col] : 0.f;
#pragma unroll
      for (int r4 = 0; r4 < 4; ++r4) {
        int row = m0 + wr * 64 + fi * 16 + (l >> 4) * 4 + r4;
        float val = acc[fi][fj][r4] + bv;
        if (biasmode == 2) val += bias[row];
        C[coff + (size_t)row * ldc + col] = f2b(val);
      }
    }
}

// ---------------- proj GEMM: 128x64, fp32 out + residual, triple-buffered --
__global__ __launch_bounds__(256) void proj_kernel(
    const ushort* __restrict__ A, const ushort* __restrict__ W,
    const float* __restrict__ bias, const float* __restrict__ resid,
    float* __restrict__ C) {
  __shared__ __align__(16) ushort As[3][128 * 32];
  __shared__ __align__(16) ushort Ws[3][64 * 32];
  const int lda = 1024, ldw = 1024, ldc = 1024, nk = 32;
  const ushort* Ab = A + (size_t)blockIdx.x * 128 * lda;
  const ushort* Wb = W + (size_t)blockIdx.y * 64 * ldw;
  int tid = threadIdx.x, l = tid & 63, w = tid >> 6;
  int wr = w >> 1, wc = w & 1;
  f32x4 acc[4][2];
#pragma unroll
  for (int i = 0; i < 4; ++i)
#pragma unroll
    for (int j = 0; j < 2; ++j) acc[i][j] = (f32x4){0.f, 0.f, 0.f, 0.f};

  int srow = l >> 2, scol = (l & 3) * 8;
  int lr = l & 15, lk = (l >> 4) * 8;

#define STAGE(bb, k0)                                                       \
  do {                                                                      \
    const ushort* ga = Ab + (size_t)(w * 32 + srow) * lda + (k0) + scol;    \
    gload16(ga, &As[bb][(w * 32) * 32]);                                    \
    gload16(ga + (size_t)16 * lda, &As[bb][(w * 32 + 16) * 32]);            \
    gload16(Wb + (size_t)(w * 16 + srow) * ldw + (k0) + scol,               \
            &Ws[bb][(w * 16) * 32]);                                        \
  } while (0)

  STAGE(0, 0);
  STAGE(1, 32);
  int cur = 0;
  for (int t = 0; t < nk; ++t) {
    if (t + 2 < nk) {
      int slot = cur + 2;
      if (slot >= 3) slot -= 3;
      STAGE(slot, (t + 2) * 32);
      asm volatile("s_waitcnt vmcnt(6)" ::: "memory");
    } else if (t + 1 < nk) {
      asm volatile("s_waitcnt vmcnt(3)" ::: "memory");
    } else {
      asm volatile("s_waitcnt vmcnt(0)" ::: "memory");
    }
    __builtin_amdgcn_s_barrier();
    __builtin_amdgcn_sched_barrier(0);
    short8 af[4], bf[2];
#pragma unroll
    for (int fi = 0; fi < 4; ++fi)
      af[fi] = *(const short8*)&As[cur][(wr * 64 + fi * 16 + lr) * 32 + lk];
#pragma unroll
    for (int fj = 0; fj < 2; ++fj)
      bf[fj] = *(const short8*)&Ws[cur][(wc * 32 + fj * 16 + lr) * 32 + lk];
    __builtin_amdgcn_s_setprio(1);
#pragma unroll
    for (int fi = 0; fi < 4; ++fi)
#pragma unroll
      for (int fj = 0; fj < 2; ++fj)
        acc[fi][fj] = __builtin_amdgcn_mfma_f32_16x16x32_bf16(
            af[fi], bf[fj], acc[fi][fj], 0, 0, 0);
    __builtin_amdgcn_s_setprio(0);
    __builtin_amdgcn_s_barrier();
    cur = cur + 1;
    if (cur >= 3) cur -= 3;
  }
#undef STAGE

  int m0 = blockIdx.x * 128, n0 = blockIdx.y * 64;
#pragma unroll
  for (int fi = 0; fi < 4; ++fi)
#pragma unroll
    for (int fj = 0; fj < 2; ++fj) {
      int col = n0 + wc * 32 + fj * 16 + lr;
      float bv = bias[col];
#pragma unroll
      for (int r4 = 0; r4 < 4; ++r4) {
        int row = m0 + wr * 64 + fi * 16 + (l >> 4) * 4 + r4;
        C[(size_t)row * ldc + col] =
            acc[fi][fj][r4] + bv + resid[(size_t)row * ldc + col];
      }
    }
}

// ---------------- Fused flash attention (swapped-QK^T, max-free softmax) ---
// grid 1024 blocks XCD-swizzled -> (bh, mtile). Block: 4 waves, 64 Q-rows.
// Pass A: lsum only (scores bounded, no max needed), per-lane accumulation,
// one cross-lane reduce at the end. Pass B: QK^T again, normalized P (nt
// stores) + PV.
__global__ __launch_bounds__(256, 3) void attn_kernel(
    const ushort* __restrict__ qb, const ushort* __restrict__ kb,
    const ushort* __restrict__ vt, float* __restrict__ att,
    ushort* __restrict__ ctrl) {
  __shared__ ushort QP_lds[64 * 72];
  __shared__ ushort K_lds[2][64 * 72];
  __shared__ ushort V_lds[2][64 * 72];

  int bid = blockIdx.x;
  int vv = ((bid & 7) << 7) + (bid >> 3);  // XCD swizzle: 8 bh per XCD
  int bh = vv >> 4, mt = vv & 15;
  int b = bh >> 4, h = bh & 15;
  int m0 = mt * 64;
  int tid = threadIdx.x, l = tid & 63, w = tid >> 6;
  int lr = l & 15, lk = (l >> 4) * 8;
  int klo = (l >> 4) * 4;

  const float SC = 0.125f * 1.44269504088896f;  // 1/8 * log2(e)

  // stage Q tile [64 rows][64 d]
#pragma unroll
  for (int it = 0; it < 2; ++it) {
    int idx = tid + it * 256;
    int row = idx >> 3, c8 = (idx & 7) * 8;
    *(uint4*)&QP_lds[row * 72 + c8] = *(const uint4*)(
        qb + (size_t)(b * 1024 + m0 + row) * 1024 + h * 64 + c8);
  }
  __syncthreads();
  short8 aq0 = *(const short8*)&QP_lds[(w * 16 + lr) * 72 + lk];
  short8 aq1 = *(const short8*)&QP_lds[(w * 16 + lr) * 72 + 32 + lk];
  __syncthreads();  // QP_lds free for P use after this

  const size_t kbase = (size_t)b * 2048 * 1024 + h * 64;
  const ushort* Kb = kb + kbase;
  int srow = tid >> 3, sc8 = (tid & 7) * 8;

  float ls = 0.f;

  // ---- pass A: row sums (max-free; scores bounded) ----
  uint4 kr0 = *(const uint4*)(Kb + (size_t)srow * 1024 + sc8);
  uint4 kr1 = *(const uint4*)(Kb + (size_t)(srow + 32) * 1024 + sc8);
  for (int t = 0; t < 32; ++t) {
    int cur = t & 1;
    *(uint4*)&K_lds[cur][srow * 72 + sc8] = kr0;
    *(uint4*)&K_lds[cur][(srow + 32) * 72 + sc8] = kr1;
    asm volatile("s_waitcnt lgkmcnt(0)" ::: "memory");
    __builtin_amdgcn_s_barrier();
    __builtin_amdgcn_sched_barrier(0);
    if (t < 31) {
      kr0 = *(const uint4*)(Kb + (size_t)(t * 64 + 64 + srow) * 1024 + sc8);
      kr1 = *(const uint4*)(Kb + (size_t)(t * 64 + 96 + srow) * 1024 + sc8);
    }
    f32x4 acc[4];
    __builtin_amdgcn_s_setprio(1);
#pragma unroll
    for (int fj = 0; fj < 4; ++fj) {
      short8 kf0 = *(const short8*)&K_lds[cur][(fj * 16 + lr) * 72 + lk];
      short8 kf1 = *(const short8*)&K_lds[cur][(fj * 16 + lr) * 72 + 32 + lk];
      f32x4 a = (f32x4){0.f, 0.f, 0.f, 0.f};
      a = __builtin_amdgcn_mfma_f32_16x16x32_bf16(kf0, aq0, a, 0, 0, 0);
      a = __builtin_amdgcn_mfma_f32_16x16x32_bf16(kf1, aq1, a, 0, 0, 0);
      acc[fj] = a;
    }
    __builtin_amdgcn_s_setprio(0);
#pragma unroll
    for (int fj = 0; fj < 4; ++fj)
#pragma unroll
      for (int r = 0; r < 4; ++r) ls += exp2f(acc[fj][r] * SC);
  }
  ls += __shfl_xor(ls, 16);
  ls += __shfl_xor(ls, 32);
  // p = exp2(s*SC - mb), mb = log2(sum)
  float mb = __log2f(ls);

  // ---- pass B: emit P + PV ----
  float* attp = att + (size_t)bh * 2048 * 1024 + (size_t)m0 * 2048;
  const ushort* Vb = vt + (size_t)bh * 64 * 2048;
  int qrow = w * 16 + lr;
  f32x4 acco[4];
#pragma unroll
  for (int fd = 0; fd < 4; ++fd) acco[fd] = (f32x4){0.f, 0.f, 0.f, 0.f};

  kr0 = *(const uint4*)(Kb + (size_t)srow * 1024 + sc8);
  kr1 = *(const uint4*)(Kb + (size_t)(srow + 32) * 1024 + sc8);
  uint4 vr0 = *(const uint4*)(Vb + (size_t)srow * 2048 + sc8);
  uint4 vr1 = *(const uint4*)(Vb + (size_t)(srow + 32) * 2048 + sc8);
  for (int t = 0; t < 32; ++t) {
    int cur = t & 1;
    int k0 = t * 64;
    *(uint4*)&K_lds[cur][srow * 72 + sc8] = kr0;
    *(uint4*)&K_lds[cur][(srow + 32) * 72 + sc8] = kr1;
    *(uint4*)&V_lds[cur][srow * 72 + sc8] = vr0;
    *(uint4*)&V_lds[cur][(srow + 32) * 72 + sc8] = vr1;
    asm volatile("s_waitcnt lgkmcnt(0)" ::: "memory");
    __builtin_amdgcn_s_barrier();
    __builtin_amdgcn_sched_barrier(0);
    if (t < 31) {
      kr0 = *(const uint4*)(Kb + (size_t)(k0 + 64 + srow) * 1024 + sc8);
      kr1 = *(const uint4*)(Kb + (size_t)(k0 + 96 + srow) * 1024 + sc8);
      vr0 = *(const uint4*)(Vb + (size_t)srow * 2048 + k0 + 64 + sc8);
      vr1 = *(const uint4*)(Vb + (size_t)(srow + 32) * 2048 + k0 + 64 + sc8);
    }
    f32x4 acc[4];
    __builtin_amdgcn_s_setprio(1);
#pragma unroll
    for (int fj = 0; fj < 4; ++fj) {
      short8 kf0 = *(const short8*)&K_lds[cur][(fj * 16 + lr) * 72 + lk];
      short8 kf1 = *(const short8*)&K_lds[cur][(fj * 16 + lr) * 72 + 32 + lk];
      f32x4 a = (f32x4){0.f, 0.f, 0.f, 0.f};
      a = __builtin_amdgcn_mfma_f32_16x16x32_bf16(kf0, aq0, a, 0, 0, 0);
      a = __builtin_amdgcn_mfma_f32_16x16x32_bf16(kf1, aq1, a, 0, 0, 0);
      acc[fj] = a;
    }
    __builtin_amdgcn_s_setprio(0);
    // emit normalized P: f32x4 nontemporal store + uint2 (4xbf16) LDS write
#pragma unroll
    for (int fj = 0; fj < 4; ++fj) {
      f32x4 p;
      p[0] = exp2f(fmaf(acc[fj][0], SC, -mb));
      p[1] = exp2f(fmaf(acc[fj][1], SC, -mb));
      p[2] = exp2f(fmaf(acc[fj][2], SC, -mb));
      p[3] = exp2f(fmaf(acc[fj][3], SC, -mb));
      __builtin_nontemporal_store(
          p, (f32x4*)(attp + (size_t)qrow * 2048 + k0 + fj * 16 + klo));
      union { uint2 u; ushort s[4]; } pk;
      pk.s[0] = f2b(p[0]);
      pk.s[1] = f2b(p[1]);
      pk.s[2] = f2b(p[2]);
      pk.s[3] = f2b(p[3]);
      *(uint2*)&QP_lds[qrow * 72 + fj * 16 + klo] = pk.u;
    }
    short8 ap0 = *(const short8*)&QP_lds[(w * 16 + lr) * 72 + lk];
    short8 ap1 = *(const short8*)&QP_lds[(w * 16 + lr) * 72 + 32 + lk];
    __builtin_amdgcn_s_setprio(1);
#pragma unroll
    for (int fd = 0; fd < 4; ++fd) {
      short8 bv0 = *(const short8*)&V_lds[cur][(fd * 16 + lr) * 72 + lk];
      short8 bv1 = *(const short8*)&V_lds[cur][(fd * 16 + lr) * 72 + 32 + lk];
      acco[fd] =
          __builtin_amdgcn_mfma_f32_16x16x32_bf16(ap0, bv0, acco[fd], 0, 0, 0);
      acco[fd] =
          __builtin_amdgcn_mfma_f32_16x16x32_bf16(ap1, bv1, acco[fd], 0, 0, 0);
    }
    __builtin_amdgcn_s_setprio(0);
  }

#pragma unroll
  for (int fd = 0; fd < 4; ++fd)
#pragma unroll
    for (int r = 0; r < 4; ++r) {
      int wrow = w * 16 + (l >> 4) * 4 + r;
      ctrl[(size_t)(b * 1024 + m0 + wrow) * 1024 + h * 64 + fd * 16 + lr] =
          f2b(acco[fd][r]);
    }
}

extern "C" void kernel_launch(void* const* d_in, const int* in_sizes, int n_in,
                              void* d_out, int out_size, void* d_ws,
                              size_t ws_size, hipStream_t stream) {
  const float* input = (const float*)d_in[0];
  const float* output = (const float*)d_in[1];
  const float* q_w = (const float*)d_in[2];
  const float* q_b = (const float*)d_in[3];
  const float* k_w = (const float*)d_in[4];
  const float* k_b = (const float*)d_in[5];
  const float* v_w = (const float*)d_in[6];
  const float* v_b = (const float*)d_in[7];
  const float* p_w = (const float*)d_in[8];
  const float* p_b = (const float*)d_in[9];
  const float* ln_in_g = (const float*)d_in[10];
  const float* ln_in_b = (const float*)d_in[11];
  const float* ln_out_g = (const float*)d_in[12];
  const float* ln_out_b = (const float*)d_in[13];

  ushort* ws = (ushort*)d_ws;
  ushort* i_ln = ws;                    // 4*2048*768  = 6291456
  ushort* o_ln = i_ln + 6291456;        // 4194304
  ushort* qb = o_ln + 4194304;          // 4194304
  ushort* kb = qb + 4194304;            // 8388608
  ushort* vt = kb + 8388608;            // 8388608  [4][1024 d][2048 k]
  ushort* ctrl = vt + 8388608;          // 4194304
  ushort* qwb = ctrl + 4194304;         // 1048576
  ushort* kwb = qwb + 1048576;          // 786432
  ushort* vwb = kwb + 786432;           // 786432
  ushort* pwb = vwb + 786432;           // 1048576

  float* att = (float*)d_out;
  float* out2 = att + 134217728LL;

  // prep: weight cvt + both LNs, one launch
  prep_kernel<<<15872, 256, 0, stream>>>(q_w, qwb, k_w, kwb, v_w, vwb, p_w,
                                         pwb, input, ln_in_g, ln_in_b, i_ln,
                                         output, ln_out_g, ln_out_b, o_ln);

  // q + k + vt GEMMs in one launch (128x128 tiles, m97 structure)
  qkv_kernel<<<1280, 256, 0, stream>>>(o_ln, i_ln, qwb, kwb, vwb, q_b, k_b,
                                       v_b, qb, kb, vt);

  // fused attention: scores + softmax + P-write + PV (64 Q-rows/block)
  attn_kernel<<<dim3(1024), 256, 0, stream>>>(qb, kb, vt, att, ctrl);

  // out = output + ctrl @ proj_w^T + proj_b (fp32) M=4096 N=1024 K=1024
  proj_kernel<<<dim3(32, 16), 256, 0, stream>>>(ctrl, pwb, p_b, output, out2);
}